// Round 4
// baseline (87.990 us; speedup 1.0000x reference)
//
#include <hip/hip_runtime.h>

constexpr int N   = 256;
constexpr int OUT = 32;
constexpr int OPG = 8;           // outputs per o-group
constexpr int OG  = OUT / OPG;   // 4 o-groups
constexpr int M2  = 32896;       // C(257,2) = 4112 * 8
constexpr int M3  = 2829056;     // C(258,3) = 353632 * 8
constexpr int P3  = M3 / 8;      // 353632 pairs (8 floats = 32 B each)
constexpr int P2  = M2 / 8;      // 4112 pairs
constexpr int BX  = 256;         // blocks per o-group; grid = (256,4) = 1024 = 4/CU
constexpr int K3  = P3 / BX;     // 1381
constexpr int R3  = P3 % BX;     // 96  (first 96 blocks take one extra pair)
constexpr int K2  = P2 / BX;     // 16
constexpr int R2  = P2 % BX;     // 16
constexpr int IT3 = (K3 + 1 + 255) / 256;   // 6 guarded iterations

typedef float f32x4 __attribute__((ext_vector_type(4)));

__device__ __forceinline__ int c3_tail(int s) {
    return s * (s + 1) * (s + 2) / 6;   // C(s+2,3)
}

__global__ __launch_bounds__(256, 4) void poly_partial(
    const float* __restrict__ x, const float* __restrict__ c2,
    const float* __restrict__ c3, float* __restrict__ partial)
{
    __shared__ float xs[N];
    const int tid = threadIdx.x;
    if (tid < N) xs[tid] = x[tid];
    __syncthreads();

    const int bx = blockIdx.x;
    const int g  = blockIdx.y;               // outputs g*8 .. g*8+7

    float acc[OPG];
#pragma unroll
    for (int oo = 0; oo < OPG; ++oo) acc[oo] = 0.f;

    // ---- degree-3: contiguous pair range per block, balanced to +-1 pair ----
    {
        const int s3 = bx * K3 + (bx < R3 ? bx : R3);
        const int n3 = K3 + (bx < R3 ? 1 : 0);
        const float* __restrict__ c3g = c3 + (size_t)g * OPG * M3;
        for (int it = 0; it < IT3; ++it) {
            const int r = it * 256 + tid;        // local pair index
            if (r < n3) {
                const int base = (s3 + r) * 8;   // monomial index of first of 8
                // decode base -> (i,j,k), i<=j<=k, lex multiset order
                int lo = 0, hi = N - 1;
                while (lo < hi) {                       // find i
                    int mid = (lo + hi + 1) >> 1;
                    int O = M3 - c3_tail(N - mid);
                    if (O <= base) lo = mid; else hi = mid - 1;
                }
                const int i = lo;
                const int s = N - i;
                const int rem = base - (M3 - c3_tail(s));
                lo = 0; hi = s - 1;
                while (lo < hi) {                       // find a = j - i
                    int mid = (lo + hi + 1) >> 1;
                    int A = mid * s - (mid * (mid - 1)) / 2;
                    if (A <= rem) lo = mid; else hi = mid - 1;
                }
                const int a = lo;
                int ii = i, j = i + a, k = j + (rem - (a * s - (a * (a - 1)) / 2));

                float v[8];
#pragma unroll
                for (int t = 0; t < 8; ++t) {
                    v[t] = xs[ii] * xs[j] * xs[k];
                    ++k;                                 // next multiset
                    if (k == N) { ++j; if (j == N) { ++ii; j = ii; } k = j; }
                }
                const float* p = c3g + (size_t)base;
#pragma unroll
                for (int oo = 0; oo < OPG; ++oo) {
                    const float* sp = p + (size_t)oo * M3;
                    const f32x4 ca = __builtin_nontemporal_load(
                        reinterpret_cast<const f32x4*>(sp));
                    const f32x4 cb = __builtin_nontemporal_load(
                        reinterpret_cast<const f32x4*>(sp + 4));
                    acc[oo] += ca[0] * v[0] + ca[1] * v[1] + ca[2] * v[2] + ca[3] * v[3]
                             + cb[0] * v[4] + cb[1] * v[5] + cb[2] * v[6] + cb[3] * v[7];
                }
            }
        }
    }

    // ---- degree-2: 16-17 pairs per block, one guarded iteration ----
    {
        const int s2 = bx * K2 + (bx < R2 ? bx : R2);
        const int n2 = K2 + (bx < R2 ? 1 : 0);
        if (tid < n2) {
            const int base = (s2 + tid) * 8;
            int lo = 0, hi = N - 1;
            while (lo < hi) {                       // find j
                int mid = (lo + hi + 1) >> 1;
                int O = mid * N - (mid * (mid - 1)) / 2;
                if (O <= base) lo = mid; else hi = mid - 1;
            }
            int j = lo;
            int k = j + (base - (j * N - (j * (j - 1)) / 2));
            float v[8];
#pragma unroll
            for (int t = 0; t < 8; ++t) {
                v[t] = xs[j] * xs[k];
                ++k;
                if (k == N) { ++j; k = j; }
            }
            const float* p = c2 + (size_t)g * OPG * M2 + base;
#pragma unroll
            for (int oo = 0; oo < OPG; ++oo) {
                const float* sp = p + (size_t)oo * M2;
                const f32x4 ca = __builtin_nontemporal_load(
                    reinterpret_cast<const f32x4*>(sp));
                const f32x4 cb = __builtin_nontemporal_load(
                    reinterpret_cast<const f32x4*>(sp + 4));
                acc[oo] += ca[0] * v[0] + ca[1] * v[1] + ca[2] * v[2] + ca[3] * v[3]
                         + cb[0] * v[4] + cb[1] * v[5] + cb[2] * v[6] + cb[3] * v[7];
            }
        }
    }

    // ---- block reduction: 4 waves -> partial[(g*BX+bx)*8 + oo] ----
    __shared__ float red[4][OPG];
    const int lane = tid & 63, wid = tid >> 6;
#pragma unroll
    for (int oo = 0; oo < OPG; ++oo) {
        float a = acc[oo];
#pragma unroll
        for (int off = 32; off > 0; off >>= 1) a += __shfl_down(a, off);
        if (lane == 0) red[wid][oo] = a;
    }
    __syncthreads();
    if (tid < OPG) {
        partial[((size_t)g * BX + bx) * OPG + tid] =
            red[0][tid] + red[1][tid] + red[2][tid] + red[3][tid];
    }
}

__global__ __launch_bounds__(256) void poly_final(
    const float* __restrict__ partial, const float* __restrict__ x,
    const float* __restrict__ c0, const float* __restrict__ c1,
    float* __restrict__ out)
{
    const int o = blockIdx.x;                 // one output per block
    const int g = o >> 3, oo = o & 7;
    const int tid = threadIdx.x;

    float a = partial[((size_t)g * BX + tid) * OPG + oo]
            + c1[o * N + tid] * x[tid];       // degree-1 term fused

    __shared__ float red[4];
    const int lane = tid & 63, wid = tid >> 6;
#pragma unroll
    for (int off = 32; off > 0; off >>= 1) a += __shfl_down(a, off);
    if (lane == 0) red[wid] = a;
    __syncthreads();
    if (tid == 0)
        out[o] = red[0] + red[1] + red[2] + red[3] + c0[o];
}

extern "C" void kernel_launch(void* const* d_in, const int* in_sizes, int n_in,
                              void* d_out, int out_size, void* d_ws, size_t ws_size,
                              hipStream_t stream) {
    const float* x  = (const float*)d_in[0];
    const float* c0 = (const float*)d_in[1];
    const float* c1 = (const float*)d_in[2];
    const float* c2 = (const float*)d_in[3];
    const float* c3 = (const float*)d_in[4];
    float* out     = (float*)d_out;
    float* partial = (float*)d_ws;   // OG*BX*OPG = 8192 floats = 32 KB

    dim3 grid(BX, OG);
    poly_partial<<<grid, 256, 0, stream>>>(x, c2, c3, partial);
    poly_final<<<OUT, 256, 0, stream>>>(partial, x, c0, c1, out);
}

// Round 5
// 66.899 us; speedup vs baseline: 1.3153x; 1.3153x over previous
//
#include <hip/hip_runtime.h>

constexpr int N   = 256;
constexpr int OUT = 32;
constexpr int OPG = 8;           // outputs per o-group
constexpr int OG  = OUT / OPG;   // 4 o-groups
constexpr int M2  = 32896;       // C(257,2)
constexpr int M3  = 2829056;     // C(258,3)
constexpr int Q3  = M3 / 4;      // 707264 float4-quads
constexpr int Q2  = M2 / 4;      // 8224
constexpr int BX  = 256;         // blocks per o-group; grid (256,4) = 1024 = 4/CU
constexpr int IT3 = 11;          // ceil(Q3 / (BX*256))
constexpr int D2_FIRST = 208;    // blocks [208,256) also handle deg-2

typedef float f32x4 __attribute__((ext_vector_type(4)));

__device__ __forceinline__ int c3_tail(int s) {
    return s * (s + 1) * (s + 2) / 6;   // C(s+2,3)
}

// One deg-3 pipeline step: prefetch quads for IT+1 into `pref`,
// then decode + FMA iteration IT from `cons`. Interleaved layout:
// quad index q = q0 + IT*65536 (same pattern as the 69.4us kernel).
template<int IT>
__device__ __forceinline__ void step3(const float* __restrict__ c3g,
                                      const float* xs, int q0,
                                      f32x4 (&cons)[OPG], f32x4 (&pref)[OPG],
                                      float (&acc)[OPG])
{
    if constexpr (IT + 1 < IT3) {
        const int qn = q0 + (IT + 1) * (BX * 256);
        if (qn < Q3) {
            const float* pn = c3g + (size_t)qn * 4;
#pragma unroll
            for (int oo = 0; oo < OPG; ++oo)
                pref[oo] = __builtin_nontemporal_load(
                    reinterpret_cast<const f32x4*>(pn + (size_t)oo * M3));
        }
    }
    const int q = q0 + IT * (BX * 256);
    if (q < Q3) {
        const int base = q * 4;
        // decode base -> (i,j,k), i<=j<=k, lex multiset order
        int lo = 0, hi = N - 1;
        while (lo < hi) {                       // find i
            int mid = (lo + hi + 1) >> 1;
            int O = M3 - c3_tail(N - mid);
            if (O <= base) lo = mid; else hi = mid - 1;
        }
        const int i0 = lo;
        const int s = N - i0;
        const int rem = base - (M3 - c3_tail(s));
        lo = 0; hi = s - 1;
        while (lo < hi) {                       // find a = j - i
            int mid = (lo + hi + 1) >> 1;
            int A = mid * s - (mid * (mid - 1)) / 2;
            if (A <= rem) lo = mid; else hi = mid - 1;
        }
        const int a = lo;
        int ii = i0, j = i0 + a, k = j + (rem - (a * s - (a * (a - 1)) / 2));

        float pre = xs[ii] * xs[j];             // CSE: 6 LDS reads/quad, not 12
        float v[4];
#pragma unroll
        for (int t = 0; t < 4; ++t) {
            v[t] = pre * xs[k];
            ++k;                                 // next multiset
            if (k == N) {
                ++j; if (j == N) { ++ii; j = ii; }
                k = j; pre = xs[ii] * xs[j];
            }
        }
#pragma unroll
        for (int oo = 0; oo < OPG; ++oo)
            acc[oo] += cons[oo][0] * v[0] + cons[oo][1] * v[1]
                     + cons[oo][2] * v[2] + cons[oo][3] * v[3];
    }
}

__global__ __launch_bounds__(256, 4) void poly_partial(
    const float* __restrict__ x, const float* __restrict__ c2,
    const float* __restrict__ c3, float* __restrict__ partial)
{
    __shared__ float xs[N];
    const int tid = threadIdx.x;
    if (tid < N) xs[tid] = x[tid];
    __syncthreads();

    const int bx = blockIdx.x;
    const int g  = blockIdx.y;               // outputs g*8 .. g*8+7

    float acc[OPG];
    f32x4 bufA[OPG], bufB[OPG];
#pragma unroll
    for (int oo = 0; oo < OPG; ++oo) {
        acc[oo] = 0.f;
        bufA[oo] = f32x4{0.f, 0.f, 0.f, 0.f};
        bufB[oo] = f32x4{0.f, 0.f, 0.f, 0.f};
    }

    const float* __restrict__ c3g = c3 + (size_t)g * OPG * M3;
    const int q0 = bx * 256 + tid;            // < 65536 < Q3: it=0 always valid

    // prologue: load iteration 0
    {
        const float* p0 = c3g + (size_t)q0 * 4;
#pragma unroll
        for (int oo = 0; oo < OPG; ++oo)
            bufA[oo] = __builtin_nontemporal_load(
                reinterpret_cast<const f32x4*>(p0 + (size_t)oo * M3));
    }
    // 11 fully-unrolled pipelined steps (ping-pong A/B)
    step3<0>(c3g, xs, q0, bufA, bufB, acc);
    step3<1>(c3g, xs, q0, bufB, bufA, acc);
    step3<2>(c3g, xs, q0, bufA, bufB, acc);
    step3<3>(c3g, xs, q0, bufB, bufA, acc);
    step3<4>(c3g, xs, q0, bufA, bufB, acc);
    step3<5>(c3g, xs, q0, bufB, bufA, acc);
    step3<6>(c3g, xs, q0, bufA, bufB, acc);
    step3<7>(c3g, xs, q0, bufB, bufA, acc);
    step3<8>(c3g, xs, q0, bufA, bufB, acc);
    step3<9>(c3g, xs, q0, bufB, bufA, acc);
    step3<10>(c3g, xs, q0, bufA, bufB, acc);

    // ---- degree-2: blocks idle in deg-3's ragged 11th iteration ----
    if (bx >= D2_FIRST) {
        const int qq = (bx - D2_FIRST) * 256 + tid;
        if (qq < Q2) {
            const int base = qq * 4;
            int lo = 0, hi = N - 1;
            while (lo < hi) {                       // find j
                int mid = (lo + hi + 1) >> 1;
                int O = mid * N - (mid * (mid - 1)) / 2;
                if (O <= base) lo = mid; else hi = mid - 1;
            }
            int j = lo;
            int k = j + (base - (j * N - (j * (j - 1)) / 2));
            float pre = xs[j];
            float v[4];
#pragma unroll
            for (int t = 0; t < 4; ++t) {
                v[t] = pre * xs[k];
                ++k;
                if (k == N) { ++j; k = j; pre = xs[j]; }
            }
            const float* p = c2 + (size_t)g * OPG * M2 + base;
#pragma unroll
            for (int oo = 0; oo < OPG; ++oo) {
                const f32x4 c = __builtin_nontemporal_load(
                    reinterpret_cast<const f32x4*>(p + (size_t)oo * M2));
                acc[oo] += c[0] * v[0] + c[1] * v[1] + c[2] * v[2] + c[3] * v[3];
            }
        }
    }

    // ---- block reduction: 4 waves -> partial[(g*BX+bx)*8 + oo] ----
    __shared__ float red[4][OPG];
    const int lane = tid & 63, wid = tid >> 6;
#pragma unroll
    for (int oo = 0; oo < OPG; ++oo) {
        float a = acc[oo];
#pragma unroll
        for (int off = 32; off > 0; off >>= 1) a += __shfl_down(a, off);
        if (lane == 0) red[wid][oo] = a;
    }
    __syncthreads();
    if (tid < OPG) {
        partial[((size_t)g * BX + bx) * OPG + tid] =
            red[0][tid] + red[1][tid] + red[2][tid] + red[3][tid];
    }
}

__global__ __launch_bounds__(256) void poly_final(
    const float* __restrict__ partial, const float* __restrict__ x,
    const float* __restrict__ c0, const float* __restrict__ c1,
    float* __restrict__ out)
{
    const int o = blockIdx.x;                 // one output per block
    const int g = o >> 3, oo = o & 7;
    const int tid = threadIdx.x;

    float a = partial[((size_t)g * BX + tid) * OPG + oo]
            + c1[o * N + tid] * x[tid];       // degree-1 term fused

    __shared__ float red[4];
    const int lane = tid & 63, wid = tid >> 6;
#pragma unroll
    for (int off = 32; off > 0; off >>= 1) a += __shfl_down(a, off);
    if (lane == 0) red[wid] = a;
    __syncthreads();
    if (tid == 0)
        out[o] = red[0] + red[1] + red[2] + red[3] + c0[o];
}

extern "C" void kernel_launch(void* const* d_in, const int* in_sizes, int n_in,
                              void* d_out, int out_size, void* d_ws, size_t ws_size,
                              hipStream_t stream) {
    const float* x  = (const float*)d_in[0];
    const float* c0 = (const float*)d_in[1];
    const float* c1 = (const float*)d_in[2];
    const float* c2 = (const float*)d_in[3];
    const float* c3 = (const float*)d_in[4];
    float* out     = (float*)d_out;
    float* partial = (float*)d_ws;   // OG*BX*OPG = 8192 floats = 32 KB

    dim3 grid(BX, OG);
    poly_partial<<<grid, 256, 0, stream>>>(x, c2, c3, partial);
    poly_final<<<OUT, 256, 0, stream>>>(partial, x, c0, c1, out);
}